// Round 12
// baseline (10298.820 us; speedup 1.0000x reference)
//
#include <hip/hip_runtime.h>
#include <hip/hip_fp16.h>
#include <math.h>

#define T_LEN 2048
#define NB 8
#define DD 512
#define HH 512
#define G4 2048   // 4*H
#define CAT2H 1024

typedef _Float16 h2_t __attribute__((ext_vector_type(2)));

__device__ __forceinline__ h2_t f2h2(float x, float y) {
  h2_t r; r[0] = (_Float16)x; r[1] = (_Float16)y; return r;
}

// ---------- vector load helpers (fp32 or fp16 -> float4) ----------
__device__ __forceinline__ float4 ld4(const float* p) { return *(const float4*)p; }
__device__ __forceinline__ float4 ld4(const __half* p) {
  const __half2 a = *(const __half2*)p;
  const __half2 b = *(const __half2*)(p + 2);
  return make_float4(__half2float(a.x), __half2float(a.y),
                     __half2float(b.x), __half2float(b.y));
}
__device__ __forceinline__ void st4(float* p, float4 v) { *(float4*)p = v; }
__device__ __forceinline__ void st4(__half* p, float4 v) {
  *(__half2*)p = __floats2half2_rn(v.x, v.y);
  *(__half2*)(p + 2) = __floats2half2_rn(v.z, v.w);
}

// -------- tiled GEMM + bias, fdot2 inner loop (fp16 staged, fp32 accum) --------
// C = A(MxK) @ B(KxN) + bias. blockIdx.y selects (B0,bias0,C0)/(B1,bias1,C1)
// so the two per-layer input-projection GEMMs run in ONE dispatch.
template <typename TA, typename TC>
__global__ __launch_bounds__(256) void gemm_bias(
    const TA* __restrict__ A, const float* __restrict__ B0,
    const float* __restrict__ B1, const float* __restrict__ bias0,
    const float* __restrict__ bias1, TC* __restrict__ C0, TC* __restrict__ C1,
    int M, int N, int K) {
  const float* __restrict__ B = blockIdx.y ? B1 : B0;
  const float* __restrict__ bias = blockIdx.y ? bias1 : bias0;
  TC* __restrict__ C = blockIdx.y ? C1 : C0;
  __shared__ h2_t As2[8][132];
  __shared__ h2_t Bs2[8][132];
  const int nTiles = N >> 7;
  const int bx = blockIdx.x % nTiles;
  const int by = blockIdx.x / nTiles;
  const int tid = threadIdx.x;
  const int tx = tid & 15, ty = tid >> 4;
  const TA* Ab = A + (size_t)by * 128 * K;
  const float* Bb = B + ((size_t)bx << 7);
  float acc[8][8];
#pragma unroll
  for (int i = 0; i < 8; i++)
#pragma unroll
    for (int j = 0; j < 8; j++) acc[i][j] = 0.f;

  for (int k0 = 0; k0 < K; k0 += 16) {
    __syncthreads();
#pragma unroll
    for (int i = 0; i < 2; i++) {
      int idx = i * 256 + tid;
      int m = idx >> 2, kv = idx & 3;
      float4 va = ld4(Ab + (size_t)m * K + k0 + kv * 4);
      As2[kv * 2][m] = f2h2(va.x, va.y);
      As2[kv * 2 + 1][m] = f2h2(va.z, va.w);
    }
#pragma unroll
    for (int i = 0; i < 2; i++) {
      int idx = i * 256 + tid;
      int kp = idx >> 6, n0 = (idx & 63) * 2;
      const float* bp0 = Bb + (size_t)(k0 + 2 * kp) * N + n0;
      float2 r0 = *(const float2*)bp0;
      float2 r1 = *(const float2*)(bp0 + N);
      Bs2[kp][n0] = f2h2(r0.x, r1.x);
      Bs2[kp][n0 + 1] = f2h2(r0.y, r1.y);
    }
    __syncthreads();
#pragma unroll
    for (int kp = 0; kp < 8; kp++) {
      h2_t a2[8], b2[8];
      *(float4*)&a2[0] = *(const float4*)&As2[kp][ty * 8];
      *(float4*)&a2[4] = *(const float4*)&As2[kp][ty * 8 + 4];
      *(float4*)&b2[0] = *(const float4*)&Bs2[kp][tx * 8];
      *(float4*)&b2[4] = *(const float4*)&Bs2[kp][tx * 8 + 4];
#pragma unroll
      for (int i = 0; i < 8; i++)
#pragma unroll
        for (int j = 0; j < 8; j++)
          acc[i][j] = __builtin_amdgcn_fdot2(a2[i], b2[j], acc[i][j], false);
    }
  }
  const int row0 = by * 128 + ty * 8;
  const int col0 = bx * 128 + tx * 8;
  float bv[8];
  *(float4*)&bv[0] = *(const float4*)&bias[col0];
  *(float4*)&bv[4] = *(const float4*)&bias[col0 + 4];
#pragma unroll
  for (int i = 0; i < 8; i++) {
    float4 o0 = make_float4(acc[i][0] + bv[0], acc[i][1] + bv[1],
                            acc[i][2] + bv[2], acc[i][3] + bv[3]);
    float4 o1 = make_float4(acc[i][4] + bv[4], acc[i][5] + bv[5],
                            acc[i][6] + bv[6], acc[i][7] + bv[7]);
    st4(&C[(size_t)(row0 + i) * N + col0], o0);
    st4(&C[(size_t)(row0 + i) * N + col0 + 4], o1);
  }
}

// ---------------- persistent bidirectional LSTM scan (one layer) ----------------
// R5 geometry + mailbox protocol VERBATIM (thrice-proven): 256 WGs x 512 thr;
// chain=(dir,b) -> 16 WGs; WG owns 32 units; u64 (tag|f32 h) relaxed AGENT
// atomics via LLC, double-buffered by step parity, tags unique per launch.
// R12 delta: ONE barrier per step. Thread t = u*16 + g*4 + j computes column
// (g,u) over k-quarter j (64 fdot2, fp16 weights in VGPRs). k-reduce = 2
// shfl_xor within the quad; gate gather = 3 shfl within the 16-lane group;
// cell update + publish in thread (t&15)==0 (c_state in its register). No
// partial[] LDS, no barrier C. h16 double-buffered by parity: a thread cannot
// get 2 steps ahead without passing the next WG barrier -> race-free.
__device__ __forceinline__ float sigmf_(float x) {
  return 1.f / (1.f + __expf(-x));
}
__device__ __forceinline__ float tanhf_(float x) {
  return 1.f - 2.f / (1.f + __expf(2.f * x));
}

__global__ __launch_bounds__(512, 2) void lstm_scan(
    const __half* __restrict__ Pf, const __half* __restrict__ Pb,
    const float* __restrict__ Whf, const float* __restrict__ Whb,
    const int* __restrict__ seqlen, __half* __restrict__ cat,
    unsigned long long* hbuf, float* diag, int tagbase) {
  const int w = blockIdx.x;
  const int chain = w & 15;
  const int us = w >> 4;
  const int dir = chain & 1;
  const int b = chain >> 1;
  const int t = threadIdx.x;
  const int lane = t & 63;
  const int u = t >> 4;         // 0..31: unit within slice
  const int g = (t >> 2) & 3;   // gate
  const int j = t & 3;          // k-quarter
  const int C = g * HH + us * 32 + u;
  const int isPub = (t & 15) == 0;

  const float* __restrict__ Wh = dir ? Whb : Whf;
  const __half* __restrict__ P = dir ? Pb : Pf;
  const int L = seqlen[b];

  __shared__ __half h16[2][HH];

  h2_t wr2[64];
  {
    const float* wp = Wh + (size_t)(j * 128) * G4 + C;
#pragma unroll
    for (int m = 0; m < 64; m++)
      wr2[m] = f2h2(wp[(size_t)(2 * m) * G4], wp[(size_t)(2 * m + 1) * G4]);
  }
  float c_state = 0.f;

  // hbuf: [slot(2)][ci(16)][unit(512)] u64 (tag<<32 | f32 h bits)
  unsigned long long* hb_base = hbuf + ((size_t)dir * NB + b) * HH;
  const size_t slotStride = (size_t)2 * NB * HH;
  const unsigned tb = (unsigned)tagbase;

  if (isPub) {  // init slot 0: h(-1)=0 tagged tb for own unit
    __hip_atomic_store(hb_base + us * 32 + u, ((unsigned long long)tb << 32),
                       __ATOMIC_RELAXED, __HIP_MEMORY_SCOPE_AGENT);
  }

  for (int s = 0; s < T_LEN; s++) {
    const int tin = dir ? ((s < L) ? (L - 1 - s) : s) : s;
    float p0 = 0.f, p1 = 0.f, p2 = 0.f, p3 = 0.f;
    if (isPub) {  // P prefetch for this unit's 4 gates; hides under the spin
      const __half* pr = P + ((size_t)b * T_LEN + tin) * G4 + us * 32 + u;
      p0 = __half2float(pr[0]);
      p1 = __half2float(pr[HH]);
      p2 = __half2float(pr[2 * HH]);
      p3 = __half2float(pr[3 * HH]);
    }

    // spin: unit t must carry tag == tb+s (R5 protocol, unchanged)
    int dead = 0;
    {
      const unsigned want = tb + (unsigned)s;
      unsigned long long* hp = hb_base + (size_t)(s & 1) * slotStride + t;
      unsigned long long v;
      int tries = 0;
      for (;;) {
        v = __hip_atomic_load(hp, __ATOMIC_RELAXED, __HIP_MEMORY_SCOPE_AGENT);
        if ((unsigned)(v >> 32) == want) break;
        if (++tries > (1 << 20)) { dead = 1; break; }
      }
      h16[s & 1][t] = __float2half(__uint_as_float((unsigned)v));
    }
    if (__syncthreads_or(dead)) {  // the ONLY barrier per step
      if (t == 0) { atomicAdd(diag + 1, 1.0f); diag[2] = (float)s; }
      break;
    }

    float a = 0.f;
    {
      const __half* hk = &h16[s & 1][j * 128];
#pragma unroll
      for (int i = 0; i < 16; i++) {
        float4 hv4 = *(const float4*)&hk[i * 8];  // 8 halfs
        const h2_t* hp2 = (const h2_t*)&hv4;
        a = __builtin_amdgcn_fdot2(hp2[0], wr2[i * 4 + 0], a, false);
        a = __builtin_amdgcn_fdot2(hp2[1], wr2[i * 4 + 1], a, false);
        a = __builtin_amdgcn_fdot2(hp2[2], wr2[i * 4 + 2], a, false);
        a = __builtin_amdgcn_fdot2(hp2[3], wr2[i * 4 + 3], a, false);
      }
    }
    // k-reduce within quad (j dimension)
    a += __shfl_xor(a, 1, 64);
    a += __shfl_xor(a, 2, 64);
    // gate gather within the 16-lane unit group
    const int base = lane & ~15;
    float d0 = __shfl(a, base + 0, 64);
    float d1 = __shfl(a, base + 4, 64);
    float d2 = __shfl(a, base + 8, 64);
    float d3 = __shfl(a, base + 12, 64);

    if (isPub) {
      float g0 = p0 + d0, g1 = p1 + d1, g2 = p2 + d2, g3 = p3 + d3;
      c_state = sigmf_(g1) * c_state + sigmf_(g0) * tanhf_(g2);
      float hn = sigmf_(g3) * tanhf_(c_state);
      unsigned long long pv =
          ((unsigned long long)(tb + (unsigned)s + 1u) << 32) |
          (unsigned long long)__float_as_uint(hn);
      __hip_atomic_store(
          hb_base + (size_t)((s + 1) & 1) * slotStride + us * 32 + u, pv,
          __ATOMIC_RELAXED, __HIP_MEMORY_SCOPE_AGENT);
      cat[((size_t)b * T_LEN + tin) * CAT2H + dir * HH + us * 32 + u] =
          __float2half(hn);
    }
    // no trailing barrier: h16 is parity double-buffered; a thread reaching
    // step s+2's spin (same parity as s) must first pass barrier B(s+1),
    // which every step-s reader also passes.
  }
}

// Failure-signature marker: writes a decodable code into out[0] ONLY on failure.
__global__ void diag_mark(const float* diag, float* out, float code_ws, int wsfail) {
  if (wsfail) { out[0] = code_ws; return; }
  float nd = diag[1];
  if (nd > 0.f) out[0] = 1.0e7f + nd * 1.0e4f + diag[2];
}

extern "C" void kernel_launch(void* const* d_in, const int* in_sizes, int n_in,
                              void* d_out, int out_size, void* d_ws, size_t ws_size,
                              hipStream_t stream) {
  const float* inputs = (const float*)d_in[0];
  const int* seqlen = (const int*)d_in[1];
  const float* Wx_f = (const float*)d_in[2];
  const float* Wh_f = (const float*)d_in[3];
  const float* b_f  = (const float*)d_in[4];
  const float* Wx_b = (const float*)d_in[5];
  const float* Wh_b = (const float*)d_in[6];
  const float* b_b  = (const float*)d_in[7];
  const float* Wp   = (const float*)d_in[8];
  const float* bp   = (const float*)d_in[9];
  float* out = (float*)d_out;

  // ws: diag(256B) | hbuf u64 @256 (128KiB) | Pf | Pb | cat | x1 (fp16)
  const size_t oHB = 256;
  const size_t szHB = (size_t)2 * 16 * HH * sizeof(unsigned long long);  // 131072
  const size_t oPf = oHB + szHB;
  const size_t oPb = oPf + 67108864ull;
  const size_t oCat = oPb + 67108864ull;
  const size_t oX1 = oCat + 33554432ull;
  const size_t need = oX1 + 16777216ull;

  if (ws_size < need) {
    hipMemsetAsync(d_out, 0, (size_t)out_size * sizeof(float), stream);
    float code = 1.0e8f + (float)(ws_size / (1024.0 * 1024.0)) * 10.0f;
    diag_mark<<<1, 1, 0, stream>>>(nullptr, out, code, 1);
    return;
  }
  char* ws = (char*)d_ws;
  float* diag = (float*)ws;
  unsigned long long* hbuf = (unsigned long long*)(ws + oHB);
  __half* Pf = (__half*)(ws + oPf);
  __half* Pb = (__half*)(ws + oPb);
  __half* cat = (__half*)(ws + oCat);
  __half* x1 = (__half*)(ws + oX1);

  hipMemsetAsync(diag, 0, 256, stream);

  const int MM = NB * T_LEN;  // 16384

  // ---- layer 0: both input projections in ONE dispatch (blockIdx.y) ----
  gemm_bias<float, __half>
      <<<dim3((MM / 128) * (G4 / 128), 2), dim3(256), 0, stream>>>(
          inputs, Wx_f, Wx_b, b_f, b_b, Pf, Pb, MM, G4, DD);
  lstm_scan<<<dim3(256), dim3(512), 0, stream>>>(Pf, Pb, Wh_f, Wh_b, seqlen, cat,
                                                 hbuf, diag, 1);
  gemm_bias<__half, __half>
      <<<dim3((MM / 128) * (DD / 128), 1), dim3(256), 0, stream>>>(
          cat, Wp, Wp, bp, bp, x1, x1, MM, DD, CAT2H);

  // ---- layer 1 ----
  gemm_bias<__half, __half>
      <<<dim3((MM / 128) * (G4 / 128), 2), dim3(256), 0, stream>>>(
          x1, Wx_f + (size_t)DD * G4, Wx_b + (size_t)DD * G4, b_f + G4, b_b + G4,
          Pf, Pb, MM, G4, DD);
  lstm_scan<<<dim3(256), dim3(512), 0, stream>>>(
      Pf, Pb, Wh_f + (size_t)HH * G4, Wh_b + (size_t)HH * G4, seqlen, cat, hbuf,
      diag, 3000);
  gemm_bias<__half, float>
      <<<dim3((MM / 128) * (DD / 128), 1), dim3(256), 0, stream>>>(
          cat, Wp + (size_t)CAT2H * DD, Wp + (size_t)CAT2H * DD, bp + DD,
          bp + DD, out, out, MM, DD, CAT2H);

  diag_mark<<<1, 1, 0, stream>>>(diag, out, 0.f, 0);
}

// Round 13
// 9660.470 us; speedup vs baseline: 1.0661x; 1.0661x over previous
//
#include <hip/hip_runtime.h>
#include <hip/hip_fp16.h>
#include <math.h>

#define T_LEN 2048
#define NB 8
#define DD 512
#define HH 512
#define G4 2048   // 4*H
#define CAT2H 1024

typedef _Float16 h2_t __attribute__((ext_vector_type(2)));

__device__ __forceinline__ h2_t f2h2(float x, float y) {
  h2_t r; r[0] = (_Float16)x; r[1] = (_Float16)y; return r;
}

// ---------- vector load helpers (fp32 or fp16 -> float4) ----------
__device__ __forceinline__ float4 ld4(const float* p) { return *(const float4*)p; }
__device__ __forceinline__ float4 ld4(const __half* p) {
  const __half2 a = *(const __half2*)p;
  const __half2 b = *(const __half2*)(p + 2);
  return make_float4(__half2float(a.x), __half2float(a.y),
                     __half2float(b.x), __half2float(b.y));
}
__device__ __forceinline__ void st4(float* p, float4 v) { *(float4*)p = v; }
__device__ __forceinline__ void st4(__half* p, float4 v) {
  *(__half2*)p = __floats2half2_rn(v.x, v.y);
  *(__half2*)(p + 2) = __floats2half2_rn(v.z, v.w);
}

// -------- tiled GEMM + bias, fdot2 inner loop (fp16 staged, fp32 accum) --------
template <typename TA, typename TC>
__global__ __launch_bounds__(256) void gemm_bias(
    const TA* __restrict__ A, const float* __restrict__ B0,
    const float* __restrict__ B1, const float* __restrict__ bias0,
    const float* __restrict__ bias1, TC* __restrict__ C0, TC* __restrict__ C1,
    int M, int N, int K) {
  const float* __restrict__ B = blockIdx.y ? B1 : B0;
  const float* __restrict__ bias = blockIdx.y ? bias1 : bias0;
  TC* __restrict__ C = blockIdx.y ? C1 : C0;
  __shared__ h2_t As2[8][132];
  __shared__ h2_t Bs2[8][132];
  const int nTiles = N >> 7;
  const int bx = blockIdx.x % nTiles;
  const int by = blockIdx.x / nTiles;
  const int tid = threadIdx.x;
  const int tx = tid & 15, ty = tid >> 4;
  const TA* Ab = A + (size_t)by * 128 * K;
  const float* Bb = B + ((size_t)bx << 7);
  float acc[8][8];
#pragma unroll
  for (int i = 0; i < 8; i++)
#pragma unroll
    for (int j = 0; j < 8; j++) acc[i][j] = 0.f;

  for (int k0 = 0; k0 < K; k0 += 16) {
    __syncthreads();
#pragma unroll
    for (int i = 0; i < 2; i++) {
      int idx = i * 256 + tid;
      int m = idx >> 2, kv = idx & 3;
      float4 va = ld4(Ab + (size_t)m * K + k0 + kv * 4);
      As2[kv * 2][m] = f2h2(va.x, va.y);
      As2[kv * 2 + 1][m] = f2h2(va.z, va.w);
    }
#pragma unroll
    for (int i = 0; i < 2; i++) {
      int idx = i * 256 + tid;
      int kp = idx >> 6, n0 = (idx & 63) * 2;
      const float* bp0 = Bb + (size_t)(k0 + 2 * kp) * N + n0;
      float2 r0 = *(const float2*)bp0;
      float2 r1 = *(const float2*)(bp0 + N);
      Bs2[kp][n0] = f2h2(r0.x, r1.x);
      Bs2[kp][n0 + 1] = f2h2(r0.y, r1.y);
    }
    __syncthreads();
#pragma unroll
    for (int kp = 0; kp < 8; kp++) {
      h2_t a2[8], b2[8];
      *(float4*)&a2[0] = *(const float4*)&As2[kp][ty * 8];
      *(float4*)&a2[4] = *(const float4*)&As2[kp][ty * 8 + 4];
      *(float4*)&b2[0] = *(const float4*)&Bs2[kp][tx * 8];
      *(float4*)&b2[4] = *(const float4*)&Bs2[kp][tx * 8 + 4];
#pragma unroll
      for (int i = 0; i < 8; i++)
#pragma unroll
        for (int j = 0; j < 8; j++)
          acc[i][j] = __builtin_amdgcn_fdot2(a2[i], b2[j], acc[i][j], false);
    }
  }
  const int row0 = by * 128 + ty * 8;
  const int col0 = bx * 128 + tx * 8;
  float bv[8];
  *(float4*)&bv[0] = *(const float4*)&bias[col0];
  *(float4*)&bv[4] = *(const float4*)&bias[col0 + 4];
#pragma unroll
  for (int i = 0; i < 8; i++) {
    float4 o0 = make_float4(acc[i][0] + bv[0], acc[i][1] + bv[1],
                            acc[i][2] + bv[2], acc[i][3] + bv[3]);
    float4 o1 = make_float4(acc[i][4] + bv[4], acc[i][5] + bv[5],
                            acc[i][6] + bv[6], acc[i][7] + bv[7]);
    st4(&C[(size_t)(row0 + i) * N + col0], o0);
    st4(&C[(size_t)(row0 + i) * N + col0 + 4], o1);
  }
}

// ---------------- persistent bidirectional LSTM scan (one layer) ----------------
// R11 body (proven 3.70ms) + R13 delta: VERIFIED intra-XCD fast path.
// Grid = 256 WGs (1/CU, co-resident). Phase 0: each WG reads HW_REG_XCC_ID,
// takes a per-XCD ticket, rendezvous on a global counter; iff every XCD counts
// exactly 32 WGs (deterministic, identical decision in all WGs), chains are
// self-assigned 2-per-XCD (FAST: sc0 L2 exchange, ~5x lower RTT than LLC),
// else blockIdx mapping + agent protocol (SAFE = R11 verbatim). Producers
// always dual-store (sc0 + agent, identical bits -> no coherence hazard);
// consumers escalate sc0->agent after 1024 misses (sticky per WG), so any
// sc0/L1 staleness degrades to ~R11 speed, never R4's 70x. Tags unique per
// launch; timeout -> diag marker. Role permutation across replays is benign
// (roles symmetric, output identical).
__device__ __forceinline__ float sigmf_(float x) {
  return 1.f / (1.f + __expf(-x));
}
__device__ __forceinline__ float tanhf_(float x) {
  return 1.f - 2.f / (1.f + __expf(2.f * x));
}

__global__ __launch_bounds__(512, 2) void lstm_scan(
    const __half* __restrict__ Pf, const __half* __restrict__ Pb,
    const float* __restrict__ Whf, const float* __restrict__ Whb,
    const int* __restrict__ seqlen, __half* __restrict__ cat,
    unsigned long long* hbuf, unsigned* ctrl, float* diag, int tagbase) {
  const int t = threadIdx.x;
  __shared__ int s_ci, s_us, s_fast, s_slow, s_abort;

  // ---- phase 0: ticketed co-location detection (one-time) ----
  if (t == 0) {
    s_slow = 0; s_abort = 0;
    int xcd = 0;
    asm volatile("s_getreg_b32 %0, hwreg(HW_REG_XCC_ID)" : "=s"(xcd));
    xcd &= 7;
    unsigned ticket = __hip_atomic_fetch_add(&ctrl[xcd], 1u, __ATOMIC_RELAXED,
                                             __HIP_MEMORY_SCOPE_AGENT);
    __hip_atomic_fetch_add(&ctrl[8], 1u, __ATOMIC_RELEASE,
                           __HIP_MEMORY_SCOPE_AGENT);
    int ok = 1, tr = 0;
    while (__hip_atomic_load(&ctrl[8], __ATOMIC_ACQUIRE,
                             __HIP_MEMORY_SCOPE_AGENT) < 256u) {
      if (++tr > (1 << 22)) { ok = 0; break; }
    }
    if (!ok) {
      s_abort = 1; s_fast = 0; s_ci = blockIdx.x & 15; s_us = blockIdx.x >> 4;
    } else {
      int bal = 1;  // counters final once done==256 -> identical view in all WGs
      for (int x = 0; x < 8; x++)
        bal &= (__hip_atomic_load(&ctrl[x], __ATOMIC_RELAXED,
                                  __HIP_MEMORY_SCOPE_AGENT) == 32u);
      if (bal && ticket < 32u) {
        s_ci = xcd * 2 + (int)(ticket >> 4);
        s_us = (int)(ticket & 15u);
        s_fast = 1;
      } else {
        s_ci = blockIdx.x & 15; s_us = blockIdx.x >> 4; s_fast = 0;
      }
    }
  }
  __syncthreads();
  if (s_abort) {
    if (t == 0) { atomicAdd(diag + 1, 1.0f); diag[2] = 9999.f; }
    return;
  }
  const int ci = s_ci, us = s_us, fastWG = s_fast;
  const int dir = ci & 1, b = ci >> 1;

  const int col = t & 127;
  const int kc = t >> 7;
  const int C = (col >> 5) * HH + us * 32 + (col & 31);
  const float* __restrict__ Wh = dir ? Whb : Whf;
  const __half* __restrict__ P = dir ? Pb : Pf;
  const int L = seqlen[b];

  __shared__ __half h16[HH];
  __shared__ float partial[4][128];

  h2_t wr2[64];
  {
    const float* wp = Wh + (size_t)(kc * 128) * G4 + C;
#pragma unroll
    for (int j = 0; j < 64; j++)
      wr2[j] = f2h2(wp[(size_t)(2 * j) * G4], wp[(size_t)(2 * j + 1) * G4]);
  }
  float c_state = 0.f;

  // hbuf: [slot(2)][ci(16)][unit(512)] u64 (tag<<32 | f32 h bits)
  unsigned long long* hb_base = hbuf + (size_t)ci * HH;
  const size_t slotStride = (size_t)2 * NB * HH;
  const unsigned tb = (unsigned)tagbase;

  if (t < 32) {  // init slot 0: h(-1)=0 tagged tb (dual store)
    unsigned long long pv = ((unsigned long long)tb << 32);
    unsigned long long* hdst = hb_base + us * 32 + t;
    if (fastWG)
      asm volatile("global_store_dwordx2 %0, %1, off sc0" ::"v"(
                       (unsigned long long)hdst),
                   "v"(pv)
                   : "memory");
    __hip_atomic_store(hdst, pv, __ATOMIC_RELAXED, __HIP_MEMORY_SCOPE_AGENT);
  }

  for (int s = 0; s < T_LEN; s++) {
    const int tin = dir ? ((s < L) ? (L - 1 - s) : s) : s;
    float p0 = 0.f, p1 = 0.f, p2 = 0.f, p3 = 0.f;
    if (t < 32) {  // P prefetch; hides under the spin
      const __half* pr = P + ((size_t)b * T_LEN + tin) * G4 + us * 32 + t;
      p0 = __half2float(pr[0]);
      p1 = __half2float(pr[HH]);
      p2 = __half2float(pr[2 * HH]);
      p3 = __half2float(pr[3 * HH]);
    }

    // spin: unit t must carry tag == tb+s; sc0 fast path with sticky escalation
    int dead = 0, slowMark = 0;
    {
      const unsigned want = tb + (unsigned)s;
      unsigned long long* hp = hb_base + (size_t)(s & 1) * slotStride + t;
      unsigned long long v;
      int fastNow = fastWG && !s_slow;
      int tries = 0;
      for (;;) {
        if (fastNow) {
          asm volatile(
              "global_load_dwordx2 %0, %1, off sc0\n\ts_waitcnt vmcnt(0)"
              : "=v"(v)
              : "v"((unsigned long long)hp)
              : "memory");
        } else {
          v = __hip_atomic_load(hp, __ATOMIC_RELAXED, __HIP_MEMORY_SCOPE_AGENT);
        }
        if ((unsigned)(v >> 32) == want) break;
        ++tries;
        if (fastNow && tries >= 1024) { fastNow = 0; slowMark = 1; }
        if (tries > (1 << 20)) { dead = 1; break; }
      }
      h16[t] = __float2half(__uint_as_float((unsigned)v));
    }
    if (slowMark) s_slow = 1;      // monotone; visible after the next barrier
    if (__syncthreads_or(dead)) {  // barrier B
      if (t == 0) { atomicAdd(diag + 1, 1.0f); diag[2] = (float)s; }
      break;
    }

    float a0 = 0.f, a1 = 0.f, a2 = 0.f, a3 = 0.f;
    const __half* hk = &h16[kc * 128];
#pragma unroll
    for (int jj = 0; jj < 16; jj++) {
      float4 hv4 = *(const float4*)&hk[jj * 8];  // wave-uniform addr: broadcast
      const h2_t* hp2 = (const h2_t*)&hv4;
      a0 = __builtin_amdgcn_fdot2(hp2[0], wr2[jj * 4 + 0], a0, false);
      a1 = __builtin_amdgcn_fdot2(hp2[1], wr2[jj * 4 + 1], a1, false);
      a2 = __builtin_amdgcn_fdot2(hp2[2], wr2[jj * 4 + 2], a2, false);
      a3 = __builtin_amdgcn_fdot2(hp2[3], wr2[jj * 4 + 3], a3, false);
    }
    partial[kc][col] = (a0 + a1) + (a2 + a3);
    __syncthreads();  // barrier C

    if (t < 32) {
      float g0 = p0, g1 = p1, g2 = p2, g3 = p3;
#pragma unroll
      for (int k2 = 0; k2 < 4; k2++) {
        g0 += partial[k2][t];
        g1 += partial[k2][32 + t];
        g2 += partial[k2][64 + t];
        g3 += partial[k2][96 + t];
      }
      c_state = sigmf_(g1) * c_state + sigmf_(g0) * tanhf_(g2);
      float hn = sigmf_(g3) * tanhf_(c_state);
      unsigned long long pv =
          ((unsigned long long)(tb + (unsigned)s + 1u) << 32) |
          (unsigned long long)__float_as_uint(hn);
      unsigned long long* hdst =
          hb_base + (size_t)((s + 1) & 1) * slotStride + us * 32 + t;
      if (fastWG)  // dual publish: local L2 (fast consumers) + LLC (safety)
        asm volatile("global_store_dwordx2 %0, %1, off sc0" ::"v"(
                         (unsigned long long)hdst),
                     "v"(pv)
                     : "memory");
      __hip_atomic_store(hdst, pv, __ATOMIC_RELAXED, __HIP_MEMORY_SCOPE_AGENT);
      cat[((size_t)b * T_LEN + tin) * CAT2H + dir * HH + us * 32 + t] =
          __float2half(hn);
    }
    // no trailing barrier: h16/partial reuse gated by barriers B/C (R5 proof).
  }
}

// Failure-signature marker: writes a decodable code into out[0] ONLY on failure.
__global__ void diag_mark(const float* diag, float* out, float code_ws, int wsfail) {
  if (wsfail) { out[0] = code_ws; return; }
  float nd = diag[1];
  if (nd > 0.f) out[0] = 1.0e7f + nd * 1.0e4f + diag[2];
}

extern "C" void kernel_launch(void* const* d_in, const int* in_sizes, int n_in,
                              void* d_out, int out_size, void* d_ws, size_t ws_size,
                              hipStream_t stream) {
  const float* inputs = (const float*)d_in[0];
  const int* seqlen = (const int*)d_in[1];
  const float* Wx_f = (const float*)d_in[2];
  const float* Wh_f = (const float*)d_in[3];
  const float* b_f  = (const float*)d_in[4];
  const float* Wx_b = (const float*)d_in[5];
  const float* Wh_b = (const float*)d_in[6];
  const float* b_b  = (const float*)d_in[7];
  const float* Wp   = (const float*)d_in[8];
  const float* bp   = (const float*)d_in[9];
  float* out = (float*)d_out;

  // ws: diag@0(64B) | ctrl0@128(64B) | ctrl1@192(64B) | hbuf u64 @256 (128KiB)
  //     | Pf | Pb | cat | x1 (fp16)
  const size_t oHB = 256;
  const size_t szHB = (size_t)2 * 16 * HH * sizeof(unsigned long long);  // 131072
  const size_t oPf = oHB + szHB;
  const size_t oPb = oPf + 67108864ull;
  const size_t oCat = oPb + 67108864ull;
  const size_t oX1 = oCat + 33554432ull;
  const size_t need = oX1 + 16777216ull;

  if (ws_size < need) {
    hipMemsetAsync(d_out, 0, (size_t)out_size * sizeof(float), stream);
    float code = 1.0e8f + (float)(ws_size / (1024.0 * 1024.0)) * 10.0f;
    diag_mark<<<1, 1, 0, stream>>>(nullptr, out, code, 1);
    return;
  }
  char* ws = (char*)d_ws;
  float* diag = (float*)ws;
  unsigned* ctrl0 = (unsigned*)(ws + 128);
  unsigned* ctrl1 = (unsigned*)(ws + 192);
  unsigned long long* hbuf = (unsigned long long*)(ws + oHB);
  __half* Pf = (__half*)(ws + oPf);
  __half* Pb = (__half*)(ws + oPb);
  __half* cat = (__half*)(ws + oCat);
  __half* x1 = (__half*)(ws + oX1);

  hipMemsetAsync(ws, 0, 256, stream);  // diag + both ctrl blocks

  const int MM = NB * T_LEN;  // 16384

  // ---- layer 0: both input projections in ONE dispatch (blockIdx.y) ----
  gemm_bias<float, __half>
      <<<dim3((MM / 128) * (G4 / 128), 2), dim3(256), 0, stream>>>(
          inputs, Wx_f, Wx_b, b_f, b_b, Pf, Pb, MM, G4, DD);
  lstm_scan<<<dim3(256), dim3(512), 0, stream>>>(Pf, Pb, Wh_f, Wh_b, seqlen, cat,
                                                 hbuf, ctrl0, diag, 1);
  gemm_bias<__half, __half>
      <<<dim3((MM / 128) * (DD / 128), 1), dim3(256), 0, stream>>>(
          cat, Wp, Wp, bp, bp, x1, x1, MM, DD, CAT2H);

  // ---- layer 1 ----
  gemm_bias<__half, __half>
      <<<dim3((MM / 128) * (G4 / 128), 2), dim3(256), 0, stream>>>(
          x1, Wx_f + (size_t)DD * G4, Wx_b + (size_t)DD * G4, b_f + G4, b_b + G4,
          Pf, Pb, MM, G4, DD);
  lstm_scan<<<dim3(256), dim3(512), 0, stream>>>(
      Pf, Pb, Wh_f + (size_t)HH * G4, Wh_b + (size_t)HH * G4, seqlen, cat, hbuf,
      ctrl1, diag, 3000);
  gemm_bias<__half, float>
      <<<dim3((MM / 128) * (DD / 128), 1), dim3(256), 0, stream>>>(
          cat, Wp + (size_t)CAT2H * DD, Wp + (size_t)CAT2H * DD, bp + DD,
          bp + DD, out, out, MM, DD, CAT2H);

  diag_mark<<<1, 1, 0, stream>>>(diag, out, 0.f, 0);
}

// Round 14
// 8082.908 us; speedup vs baseline: 1.2741x; 1.1952x over previous
//
#include <hip/hip_runtime.h>
#include <hip/hip_fp16.h>
#include <math.h>

#define T_LEN 2048
#define NB 8
#define DD 512
#define HH 512
#define G4 2048   // 4*H
#define CAT2H 1024
#define JPAD 136  // 128 + 8 halfs: per-j-block padded stride (bank-conflict-free)

typedef _Float16 h2_t __attribute__((ext_vector_type(2)));

__device__ __forceinline__ h2_t f2h2(float x, float y) {
  h2_t r; r[0] = (_Float16)x; r[1] = (_Float16)y; return r;
}

// ---------- vector load helpers (fp32 or fp16 -> float4) ----------
__device__ __forceinline__ float4 ld4(const float* p) { return *(const float4*)p; }
__device__ __forceinline__ float4 ld4(const __half* p) {
  const __half2 a = *(const __half2*)p;
  const __half2 b = *(const __half2*)(p + 2);
  return make_float4(__half2float(a.x), __half2float(a.y),
                     __half2float(b.x), __half2float(b.y));
}
__device__ __forceinline__ void st4(float* p, float4 v) { *(float4*)p = v; }
__device__ __forceinline__ void st4(__half* p, float4 v) {
  *(__half2*)p = __floats2half2_rn(v.x, v.y);
  *(__half2*)(p + 2) = __floats2half2_rn(v.z, v.w);
}

// -------- tiled GEMM + bias, fdot2 inner loop (fp16 staged, fp32 accum) --------
// C = A(MxK) @ B(KxN) + bias. blockIdx.y selects (B0,bias0,C0)/(B1,bias1,C1).
template <typename TA, typename TC>
__global__ __launch_bounds__(256) void gemm_bias(
    const TA* __restrict__ A, const float* __restrict__ B0,
    const float* __restrict__ B1, const float* __restrict__ bias0,
    const float* __restrict__ bias1, TC* __restrict__ C0, TC* __restrict__ C1,
    int M, int N, int K) {
  const float* __restrict__ B = blockIdx.y ? B1 : B0;
  const float* __restrict__ bias = blockIdx.y ? bias1 : bias0;
  TC* __restrict__ C = blockIdx.y ? C1 : C0;
  __shared__ h2_t As2[8][132];
  __shared__ h2_t Bs2[8][132];
  const int nTiles = N >> 7;
  const int bx = blockIdx.x % nTiles;
  const int by = blockIdx.x / nTiles;
  const int tid = threadIdx.x;
  const int tx = tid & 15, ty = tid >> 4;
  const TA* Ab = A + (size_t)by * 128 * K;
  const float* Bb = B + ((size_t)bx << 7);
  float acc[8][8];
#pragma unroll
  for (int i = 0; i < 8; i++)
#pragma unroll
    for (int j = 0; j < 8; j++) acc[i][j] = 0.f;

  for (int k0 = 0; k0 < K; k0 += 16) {
    __syncthreads();
#pragma unroll
    for (int i = 0; i < 2; i++) {
      int idx = i * 256 + tid;
      int m = idx >> 2, kv = idx & 3;
      float4 va = ld4(Ab + (size_t)m * K + k0 + kv * 4);
      As2[kv * 2][m] = f2h2(va.x, va.y);
      As2[kv * 2 + 1][m] = f2h2(va.z, va.w);
    }
#pragma unroll
    for (int i = 0; i < 2; i++) {
      int idx = i * 256 + tid;
      int kp = idx >> 6, n0 = (idx & 63) * 2;
      const float* bp0 = Bb + (size_t)(k0 + 2 * kp) * N + n0;
      float2 r0 = *(const float2*)bp0;
      float2 r1 = *(const float2*)(bp0 + N);
      Bs2[kp][n0] = f2h2(r0.x, r1.x);
      Bs2[kp][n0 + 1] = f2h2(r0.y, r1.y);
    }
    __syncthreads();
#pragma unroll
    for (int kp = 0; kp < 8; kp++) {
      h2_t a2[8], b2[8];
      *(float4*)&a2[0] = *(const float4*)&As2[kp][ty * 8];
      *(float4*)&a2[4] = *(const float4*)&As2[kp][ty * 8 + 4];
      *(float4*)&b2[0] = *(const float4*)&Bs2[kp][tx * 8];
      *(float4*)&b2[4] = *(const float4*)&Bs2[kp][tx * 8 + 4];
#pragma unroll
      for (int i = 0; i < 8; i++)
#pragma unroll
        for (int j = 0; j < 8; j++)
          acc[i][j] = __builtin_amdgcn_fdot2(a2[i], b2[j], acc[i][j], false);
    }
  }
  const int row0 = by * 128 + ty * 8;
  const int col0 = bx * 128 + tx * 8;
  float bv[8];
  *(float4*)&bv[0] = *(const float4*)&bias[col0];
  *(float4*)&bv[4] = *(const float4*)&bias[col0 + 4];
#pragma unroll
  for (int i = 0; i < 8; i++) {
    float4 o0 = make_float4(acc[i][0] + bv[0], acc[i][1] + bv[1],
                            acc[i][2] + bv[2], acc[i][3] + bv[3]);
    float4 o1 = make_float4(acc[i][4] + bv[4], acc[i][5] + bv[5],
                            acc[i][6] + bv[6], acc[i][7] + bv[7]);
    st4(&C[(size_t)(row0 + i) * N + col0], o0);
    st4(&C[(size_t)(row0 + i) * N + col0 + 4], o1);
  }
}

// ---------------- persistent bidirectional LSTM scan (one layer) ----------------
// R5 geometry + mailbox protocol VERBATIM (4x proven): 256 WGs x 512 thr;
// chain=(dir,b) -> 16 WGs; WG owns 32 units; u64 (tag|f32 h) relaxed AGENT
// atomics via LLC (sc0/intra-XCD ruled out: R4+R13 show sc0 loads run at LLC
// latency, non-sc0 are stale), double-buffered by step parity, unique tags.
// R14 = R12's single-barrier layout + bank-conflict fix: thread t = u*16+g*4+j
// computes column (g,u) over k-quarter j; k-reduce = 2 shfl_xor in the quad;
// gate gather = 3 shfl in the 16-lane group; cell+publish in lane (t&15)==0.
// h16 j-blocks padded to 136 halfs (272B = 68 words, 68%32=4) so the 4
// j-groups' broadcast reads hit disjoint bank sets (R12's 8e8 conflicts -> 0).
__device__ __forceinline__ float sigmf_(float x) {
  return 1.f / (1.f + __expf(-x));
}
__device__ __forceinline__ float tanhf_(float x) {
  return 1.f - 2.f / (1.f + __expf(2.f * x));
}

__global__ __launch_bounds__(512, 2) void lstm_scan(
    const __half* __restrict__ Pf, const __half* __restrict__ Pb,
    const float* __restrict__ Whf, const float* __restrict__ Whb,
    const int* __restrict__ seqlen, __half* __restrict__ cat,
    unsigned long long* hbuf, float* diag, int tagbase) {
  const int w = blockIdx.x;
  const int chain = w & 15;
  const int us = w >> 4;
  const int dir = chain & 1;
  const int b = chain >> 1;
  const int t = threadIdx.x;
  const int lane = t & 63;
  const int u = t >> 4;         // 0..31: unit within slice
  const int g = (t >> 2) & 3;   // gate
  const int j = t & 3;          // k-quarter
  const int C = g * HH + us * 32 + u;
  const int isPub = (t & 15) == 0;

  const float* __restrict__ Wh = dir ? Whb : Whf;
  const __half* __restrict__ P = dir ? Pb : Pf;
  const int L = seqlen[b];

  __shared__ __half h16[2][4 * JPAD];  // [parity][j-block padded]

  h2_t wr2[64];
  {
    const float* wp = Wh + (size_t)(j * 128) * G4 + C;
#pragma unroll
    for (int m = 0; m < 64; m++)
      wr2[m] = f2h2(wp[(size_t)(2 * m) * G4], wp[(size_t)(2 * m + 1) * G4]);
  }
  float c_state = 0.f;

  // hbuf: [slot(2)][ci(16)][unit(512)] u64 (tag<<32 | f32 h bits)
  unsigned long long* hb_base = hbuf + ((size_t)dir * NB + b) * HH;
  const size_t slotStride = (size_t)2 * NB * HH;
  const unsigned tb = (unsigned)tagbase;

  if (isPub) {  // init slot 0: h(-1)=0 tagged tb for own unit
    __hip_atomic_store(hb_base + us * 32 + u, ((unsigned long long)tb << 32),
                       __ATOMIC_RELAXED, __HIP_MEMORY_SCOPE_AGENT);
  }

  for (int s = 0; s < T_LEN; s++) {
    const int tin = dir ? ((s < L) ? (L - 1 - s) : s) : s;
    float p0 = 0.f, p1 = 0.f, p2 = 0.f, p3 = 0.f;
    if (isPub) {  // P prefetch for this unit's 4 gates; hides under the spin
      const __half* pr = P + ((size_t)b * T_LEN + tin) * G4 + us * 32 + u;
      p0 = __half2float(pr[0]);
      p1 = __half2float(pr[HH]);
      p2 = __half2float(pr[2 * HH]);
      p3 = __half2float(pr[3 * HH]);
    }

    // spin: mailbox unit t must carry tag == tb+s (R5 protocol, unchanged)
    int dead = 0;
    {
      const unsigned want = tb + (unsigned)s;
      unsigned long long* hp = hb_base + (size_t)(s & 1) * slotStride + t;
      unsigned long long v;
      int tries = 0;
      for (;;) {
        v = __hip_atomic_load(hp, __ATOMIC_RELAXED, __HIP_MEMORY_SCOPE_AGENT);
        if ((unsigned)(v >> 32) == want) break;
        if (++tries > (1 << 20)) { dead = 1; break; }
      }
      h16[s & 1][(t >> 7) * JPAD + (t & 127)] =
          __float2half(__uint_as_float((unsigned)v));
    }
    if (__syncthreads_or(dead)) {  // the ONLY barrier per step
      if (t == 0) { atomicAdd(diag + 1, 1.0f); diag[2] = (float)s; }
      break;
    }

    float a = 0.f;
    {
      const __half* hk = &h16[s & 1][j * JPAD];
#pragma unroll
      for (int i = 0; i < 16; i++) {
        float4 hv4 = *(const float4*)&hk[i * 8];  // bcast within 16-lane group
        const h2_t* hp2 = (const h2_t*)&hv4;
        a = __builtin_amdgcn_fdot2(hp2[0], wr2[i * 4 + 0], a, false);
        a = __builtin_amdgcn_fdot2(hp2[1], wr2[i * 4 + 1], a, false);
        a = __builtin_amdgcn_fdot2(hp2[2], wr2[i * 4 + 2], a, false);
        a = __builtin_amdgcn_fdot2(hp2[3], wr2[i * 4 + 3], a, false);
      }
    }
    // k-reduce within quad (j dimension)
    a += __shfl_xor(a, 1, 64);
    a += __shfl_xor(a, 2, 64);
    // gate gather within the 16-lane unit group
    const int base = lane & ~15;
    float d0 = __shfl(a, base + 0, 64);
    float d1 = __shfl(a, base + 4, 64);
    float d2 = __shfl(a, base + 8, 64);
    float d3 = __shfl(a, base + 12, 64);

    if (isPub) {
      float g0 = p0 + d0, g1 = p1 + d1, g2 = p2 + d2, g3 = p3 + d3;
      c_state = sigmf_(g1) * c_state + sigmf_(g0) * tanhf_(g2);
      float hn = sigmf_(g3) * tanhf_(c_state);
      unsigned long long pv =
          ((unsigned long long)(tb + (unsigned)s + 1u) << 32) |
          (unsigned long long)__float_as_uint(hn);
      __hip_atomic_store(
          hb_base + (size_t)((s + 1) & 1) * slotStride + us * 32 + u, pv,
          __ATOMIC_RELAXED, __HIP_MEMORY_SCOPE_AGENT);
      cat[((size_t)b * T_LEN + tin) * CAT2H + dir * HH + us * 32 + u] =
          __float2half(hn);
    }
    // no trailing barrier: h16 is parity double-buffered; writing h16[s&1]
    // again requires passing barrier(s+1), which every step-s reader passed.
  }
}

// Failure-signature marker: writes a decodable code into out[0] ONLY on failure.
__global__ void diag_mark(const float* diag, float* out, float code_ws, int wsfail) {
  if (wsfail) { out[0] = code_ws; return; }
  float nd = diag[1];
  if (nd > 0.f) out[0] = 1.0e7f + nd * 1.0e4f + diag[2];
}

extern "C" void kernel_launch(void* const* d_in, const int* in_sizes, int n_in,
                              void* d_out, int out_size, void* d_ws, size_t ws_size,
                              hipStream_t stream) {
  const float* inputs = (const float*)d_in[0];
  const int* seqlen = (const int*)d_in[1];
  const float* Wx_f = (const float*)d_in[2];
  const float* Wh_f = (const float*)d_in[3];
  const float* b_f  = (const float*)d_in[4];
  const float* Wx_b = (const float*)d_in[5];
  const float* Wh_b = (const float*)d_in[6];
  const float* b_b  = (const float*)d_in[7];
  const float* Wp   = (const float*)d_in[8];
  const float* bp   = (const float*)d_in[9];
  float* out = (float*)d_out;

  // ws: diag(256B) | hbuf u64 @256 (128KiB) | Pf | Pb | cat | x1 (fp16)
  const size_t oHB = 256;
  const size_t szHB = (size_t)2 * 16 * HH * sizeof(unsigned long long);  // 131072
  const size_t oPf = oHB + szHB;
  const size_t oPb = oPf + 67108864ull;
  const size_t oCat = oPb + 67108864ull;
  const size_t oX1 = oCat + 33554432ull;
  const size_t need = oX1 + 16777216ull;

  if (ws_size < need) {
    hipMemsetAsync(d_out, 0, (size_t)out_size * sizeof(float), stream);
    float code = 1.0e8f + (float)(ws_size / (1024.0 * 1024.0)) * 10.0f;
    diag_mark<<<1, 1, 0, stream>>>(nullptr, out, code, 1);
    return;
  }
  char* ws = (char*)d_ws;
  float* diag = (float*)ws;
  unsigned long long* hbuf = (unsigned long long*)(ws + oHB);
  __half* Pf = (__half*)(ws + oPf);
  __half* Pb = (__half*)(ws + oPb);
  __half* cat = (__half*)(ws + oCat);
  __half* x1 = (__half*)(ws + oX1);

  hipMemsetAsync(diag, 0, 256, stream);

  const int MM = NB * T_LEN;  // 16384

  // ---- layer 0: both input projections in ONE dispatch (blockIdx.y) ----
  gemm_bias<float, __half>
      <<<dim3((MM / 128) * (G4 / 128), 2), dim3(256), 0, stream>>>(
          inputs, Wx_f, Wx_b, b_f, b_b, Pf, Pb, MM, G4, DD);
  lstm_scan<<<dim3(256), dim3(512), 0, stream>>>(Pf, Pb, Wh_f, Wh_b, seqlen, cat,
                                                 hbuf, diag, 1);
  gemm_bias<__half, __half>
      <<<dim3((MM / 128) * (DD / 128), 1), dim3(256), 0, stream>>>(
          cat, Wp, Wp, bp, bp, x1, x1, MM, DD, CAT2H);

  // ---- layer 1 ----
  gemm_bias<__half, __half>
      <<<dim3((MM / 128) * (G4 / 128), 2), dim3(256), 0, stream>>>(
          x1, Wx_f + (size_t)DD * G4, Wx_b + (size_t)DD * G4, b_f + G4, b_b + G4,
          Pf, Pb, MM, G4, DD);
  lstm_scan<<<dim3(256), dim3(512), 0, stream>>>(
      Pf, Pb, Wh_f + (size_t)HH * G4, Wh_b + (size_t)HH * G4, seqlen, cat, hbuf,
      diag, 3000);
  gemm_bias<__half, float>
      <<<dim3((MM / 128) * (DD / 128), 1), dim3(256), 0, stream>>>(
          cat, Wp + (size_t)CAT2H * DD, Wp + (size_t)CAT2H * DD, bp + DD,
          bp + DD, out, out, MM, DD, CAT2H);

  diag_mark<<<1, 1, 0, stream>>>(diag, out, 0.f, 0);
}